// Round 1
// 419.210 us; speedup vs baseline: 1.0284x; 1.0284x over previous
//
#include <hip/hip_runtime.h>

// Problem constants (B,N,T,D) = (8,256,64,512)
#define Bb 8
#define Nn 256
#define Tt 64
#define Dd 512
#define NT (Nn * Tt)   // 16384

// d_out layout (all float32, concatenated in return order):
//   new_x      : Bb*NT*Dd = 67,108,864
//   new_mask   : Bb*NT    = 131,072
//   doc_seq_len: Bb       = 8
//   new_tag    : Bb*NT    = 131,072
#define O_MASK (Bb * NT * Dd)
#define O_DOC  (O_MASK + Bb * NT)
#define O_TAG  (O_DOC + Bb)

typedef float v4f __attribute__((ext_vector_type(4)));

// ---------------------------------------------------------------------------
// Kernel 1 (fused scan+map): each block re-computes the per-batch exclusive
// scan of length[] in LDS (256 elems, ~0.5us, L2-hit loads), then builds the
// gather map src[b][j] via binary search; writes new_mask, new_tag, doc.
// Removes the old 8-block scan kernel (a full-device serialization bubble).
// ---------------------------------------------------------------------------
__global__ __launch_bounds__(256) void map_kernel(const int* __restrict__ length,
                                                  const int* __restrict__ tags,
                                                  int* __restrict__ ws_src,
                                                  float* __restrict__ out_mask,
                                                  float* __restrict__ out_tag,
                                                  float* __restrict__ out_doc) {
    __shared__ int s[Nn];
    __shared__ int off[Nn + 1];
    const int tid = threadIdx.x;
    const int b = blockIdx.x >> 6;                 // 64 blocks per batch
    const int j = ((blockIdx.x & 63) << 8) | tid;  // position in [0, NT)

    const int v = length[b * Nn + tid];
    s[tid] = v;
    __syncthreads();
    // Hillis-Steele inclusive scan over 256 entries
    for (int o = 1; o < Nn; o <<= 1) {
        int t = 0;
        if (tid >= o) t = s[tid - o];
        __syncthreads();
        if (tid >= o) s[tid] += t;
        __syncthreads();
    }
    off[tid] = s[tid] - v;                 // exclusive prefix
    if (tid == Nn - 1) off[Nn] = s[Nn - 1];
    __syncthreads();

    const int doc = off[Nn];
    if (((blockIdx.x & 63) == 0) && tid == 0) out_doc[b] = (float)doc;

    int   src = -1;
    float m = 0.0f, tg = 0.0f;  // PAD_TAG = 0
    if (j < doc) {
        int lo = 0, hi = Nn - 1;
        #pragma unroll
        for (int it = 0; it < 8; ++it) {           // 2^8 = 256 segments
            int mid = (lo + hi + 1) >> 1;
            if (off[mid] <= j) lo = mid; else hi = mid - 1;
        }
        src = lo * Tt + (j - off[lo]);
        m = 1.0f;
        tg = (float)tags[b * NT + src];
    }
    ws_src[b * NT + j]   = src;
    out_mask[b * NT + j] = m;
    out_tag[b * NT + j]  = tg;
}

// ---------------------------------------------------------------------------
// Kernel 2: new_x[b,j,:] = x_gcn[b, j/T, :] + (src>=0 ? x[b, src, :] : 0)
// float4 lanes; one thread per 16B. x and out are touch-once streams ->
// nontemporal, so they don't thrash LLC against each other or evict gcn.
// ---------------------------------------------------------------------------
__global__ __launch_bounds__(256) void add_kernel(const v4f* __restrict__ x,
                                                  const v4f* __restrict__ gcn,
                                                  const int* __restrict__ ws_src,
                                                  v4f* __restrict__ out) {
    const int e4   = blockIdx.x * 256 + threadIdx.x;  // float4 index, < 2^24
    const int row  = e4 >> 7;          // / (Dd/4 = 128)
    const int c    = e4 & 127;
    const int b    = row >> 14;        // / NT
    const int j    = row & (NT - 1);
    const int node = j >> 6;           // / Tt

    v4f v = gcn[(b * Nn + node) * 128 + c];   // reused 64x -> cached
    const int src = ws_src[row];
    if (src >= 0) {
        v4f xv = __builtin_nontemporal_load(&x[((b << 14) + src) * 128 + c]);
        v += xv;
    }
    __builtin_nontemporal_store(v, &out[e4]);
}

extern "C" void kernel_launch(void* const* d_in, const int* in_sizes, int n_in,
                              void* d_out, int out_size, void* d_ws, size_t ws_size,
                              hipStream_t stream) {
    const float* x     = (const float*)d_in[0];  // (B,N,T,D)
    const float* x_gcn = (const float*)d_in[1];  // (B,N,D)
    // d_in[2] = mask — unused (mask is a prefix mask, fully determined by length)
    const int* length  = (const int*)d_in[3];    // (B,N)
    const int* tags    = (const int*)d_in[4];    // (B,N,T)

    float* out    = (float*)d_out;
    int*   ws_src = (int*)d_ws;   // Bb*NT ints

    map_kernel<<<Bb * (NT / 256), 256, 0, stream>>>(length, tags, ws_src,
                                                    out + O_MASK, out + O_TAG,
                                                    out + O_DOC);
    add_kernel<<<(Bb * NT * (Dd / 4)) / 256, 256, 0, stream>>>(
        (const v4f*)x, (const v4f*)x_gcn, ws_src, (v4f*)out);
}

// Round 2
// 411.908 us; speedup vs baseline: 1.0466x; 1.0177x over previous
//
#include <hip/hip_runtime.h>

// Problem constants (B,N,T,D) = (8,256,64,512)
#define Bb 8
#define Nn 256
#define Tt 64
#define Dd 512
#define NT (Nn * Tt)   // 16384

// d_out layout (all float32, concatenated in return order):
//   new_x      : Bb*NT*Dd = 67,108,864
//   new_mask   : Bb*NT    = 131,072
//   doc_seq_len: Bb       = 8
//   new_tag    : Bb*NT    = 131,072
#define O_MASK (Bb * NT * Dd)
#define O_DOC  (O_MASK + Bb * NT)
#define O_TAG  (O_DOC + Bb)

#define ROWS_PER_BLK 16            // 16 rows x 128 float4 = 2048 f4 per block
#define BLKS_PER_BATCH (NT / ROWS_PER_BLK)   // 1024

typedef float v4f __attribute__((ext_vector_type(4)));

// ---------------------------------------------------------------------------
// Single fused kernel. Per block (256 thr, 16 output rows of one batch):
//  1. shuffle-scan length[b][0..255] -> exclusive offsets in LDS (2 barriers)
//  2. binary-search src row for each of the 16 rows; write mask/tag/doc
//  3. streaming add: out[b,j,:] = gcn[b, j/T, :] + (valid ? x[b,src,:] : 0)
// Since ROWS_PER_BLK divides Tt, all 16 rows share one node -> gcn is ONE
// register load per thread, reused 8x. x/out are touch-once -> nontemporal.
// Scan redundancy (8192 blocks x 1KB L2-hit reads) hides under BW-bound
// streaming of co-resident blocks (VALUBusy was ~5%).
// ---------------------------------------------------------------------------
__global__ __launch_bounds__(256) void fused_kernel(const int* __restrict__ length,
                                                    const int* __restrict__ tags,
                                                    const v4f* __restrict__ x,
                                                    const v4f* __restrict__ gcn,
                                                    v4f* __restrict__ out_x,
                                                    float* __restrict__ out_mask,
                                                    float* __restrict__ out_tag,
                                                    float* __restrict__ out_doc) {
    __shared__ int off[Nn + 1];
    __shared__ int wtot[4];
    __shared__ int srcs[ROWS_PER_BLK];

    const int tid  = threadIdx.x;
    const int blk  = blockIdx.x;
    const int b    = blk >> 10;                    // / BLKS_PER_BATCH
    const int j0   = (blk & (BLKS_PER_BATCH - 1)) << 4;
    const int lane = tid & 63;
    const int wave = tid >> 6;

    // gcn load early (independent of scan); node is uniform for the block,
    // column c = tid&127 is the same for every k-iteration below.
    const int node0 = j0 >> 6;
    const v4f g = gcn[(b * Nn + node0) * 128 + (tid & 127)];

    // --- 1. scan: per-wave shuffle inclusive scan + cross-wave combine ---
    const int v = length[b * Nn + tid];
    int inc = v;
    #pragma unroll
    for (int o = 1; o < 64; o <<= 1) {
        int t = __shfl_up(inc, o, 64);
        if (lane >= o) inc += t;
    }
    if (lane == 63) wtot[wave] = inc;
    __syncthreads();
    int wpref = 0;
    #pragma unroll
    for (int w = 0; w < 3; ++w)
        if (w < wave) wpref += wtot[w];
    off[tid] = wpref + inc - v;                    // exclusive prefix
    if (tid == 255) off[Nn] = wpref + inc;         // total = doc_seq_len
    __syncthreads();

    const int doc = off[Nn];
    if ((blk & (BLKS_PER_BATCH - 1)) == 0 && tid == 0) out_doc[b] = (float)doc;

    // --- 2. map the block's 16 rows ---
    if (tid < ROWS_PER_BLK) {
        const int j = j0 + tid;
        int   src = -1;
        float m = 0.0f, tg = 0.0f;                 // PAD_TAG = 0
        if (j < doc) {
            int lo = 0, hi = Nn - 1;
            #pragma unroll
            for (int it = 0; it < 8; ++it) {       // 2^8 = 256 segments
                int mid = (lo + hi + 1) >> 1;
                if (off[mid] <= j) lo = mid; else hi = mid - 1;
            }
            src = lo * Tt + (j - off[lo]);
            m  = 1.0f;
            tg = (float)tags[b * NT + src];
        }
        srcs[tid] = src;
        out_mask[b * NT + j] = m;
        out_tag[b * NT + j]  = tg;
    }
    __syncthreads();

    // --- 3. streaming add: 2048 float4, 8 per thread, coalesced ---
    const int outbase = (b * NT + j0) * 128;       // < 2^24, int-safe
    const int xbbase  = (b << 14) * 128;
    #pragma unroll
    for (int k = 0; k < 8; ++k) {
        const int idx = k * 256 + tid;             // 0..2047
        const int r   = idx >> 7;                  // row in block, 0..15
        const int c   = idx & 127;                 // == tid & 127
        v4f val = g;
        const int src = srcs[r];
        if (src >= 0)
            val += __builtin_nontemporal_load(&x[xbbase + src * 128 + c]);
        __builtin_nontemporal_store(val, &out_x[outbase + idx]);
    }
}

extern "C" void kernel_launch(void* const* d_in, const int* in_sizes, int n_in,
                              void* d_out, int out_size, void* d_ws, size_t ws_size,
                              hipStream_t stream) {
    const float* x     = (const float*)d_in[0];  // (B,N,T,D)
    const float* x_gcn = (const float*)d_in[1];  // (B,N,D)
    // d_in[2] = mask — unused (prefix mask, fully determined by length)
    const int* length  = (const int*)d_in[3];    // (B,N)
    const int* tags    = (const int*)d_in[4];    // (B,N,T)

    float* out = (float*)d_out;

    fused_kernel<<<Bb * BLKS_PER_BATCH, 256, 0, stream>>>(
        length, tags, (const v4f*)x, (const v4f*)x_gcn,
        (v4f*)out, out + O_MASK, out + O_TAG, out + O_DOC);
}